// Round 3
// baseline (7833.064 us; speedup 1.0000x reference)
//
#include <hip/hip_runtime.h>

#define BB 4
#define NN 8192
#define SS 2048
#define KK 16
#define INCH 64
#define HH 64
#define OUTC 128
#define LEAKY_A 0.1f
#define EPSF 1e-5f

__device__ __forceinline__ float sq3(float a, float b, float c) {
    // strict IEEE ((a*a + b*b) + c*c) to match numpy reduction order, no FMA contraction
    return __fadd_rn(__fadd_rn(__fmul_rn(a, a), __fmul_rn(b, b)), __fmul_rn(c, c));
}

__device__ __forceinline__ float leaky_f(float x) { return x >= 0.f ? x : LEAKY_A * x; }

__device__ __forceinline__ int spread3(int v) {
    return (v & 1) | ((v & 2) << 2) | ((v & 4) << 4);
}

// ---------------- FPS phase 1: Morton counting-sort (1024 thr/batch) ----------
// Emits spatially-sorted SoA point arrays (+ original indices) so the iteration
// kernel's per-thread 32-point chunks are spatially tight.
__global__ __launch_bounds__(1024)
void fps_sort_kernel(const float* __restrict__ xyz,   // [B,3,N]
                     float* __restrict__ spx, float* __restrict__ spy,
                     float* __restrict__ spz, int* __restrict__ soi)
{
    int b = blockIdx.x, t = threadIdx.x;
    int lane = t & 63, wid = t >> 6;
    const float* xb = xyz + (long)b * 3 * NN;

    __shared__ unsigned short perm[NN];          // 16 KB
    __shared__ unsigned int hist[512];           // 2 KB
    __shared__ unsigned int starts[512];         // 2 KB
    __shared__ unsigned int wsum[8];
    __shared__ float wred[16][6];

    float lx[8], ly[8], lz[8];
    float mnx = 3.4e38f, mny = 3.4e38f, mnz = 3.4e38f;
    float mxx = -3.4e38f, mxy = -3.4e38f, mxz = -3.4e38f;
#pragma unroll
    for (int j = 0; j < 8; ++j) {
        int n = t * 8 + j;
        lx[j] = xb[n]; ly[j] = xb[NN + n]; lz[j] = xb[2 * NN + n];
        mnx = fminf(mnx, lx[j]); mxx = fmaxf(mxx, lx[j]);
        mny = fminf(mny, ly[j]); mxy = fmaxf(mxy, ly[j]);
        mnz = fminf(mnz, lz[j]); mxz = fmaxf(mxz, lz[j]);
    }
#pragma unroll
    for (int off = 1; off < 64; off <<= 1) {
        mnx = fminf(mnx, __shfl_xor(mnx, off)); mxx = fmaxf(mxx, __shfl_xor(mxx, off));
        mny = fminf(mny, __shfl_xor(mny, off)); mxy = fmaxf(mxy, __shfl_xor(mxy, off));
        mnz = fminf(mnz, __shfl_xor(mnz, off)); mxz = fmaxf(mxz, __shfl_xor(mxz, off));
    }
    if (lane == 0) {
        wred[wid][0] = mnx; wred[wid][1] = mny; wred[wid][2] = mnz;
        wred[wid][3] = mxx; wred[wid][4] = mxy; wred[wid][5] = mxz;
    }
    if (t < 512) hist[t] = 0;
    __syncthreads();
    mnx = wred[0][0]; mny = wred[0][1]; mnz = wred[0][2];
    mxx = wred[0][3]; mxy = wred[0][4]; mxz = wred[0][5];
#pragma unroll
    for (int w = 1; w < 16; ++w) {
        mnx = fminf(mnx, wred[w][0]); mny = fminf(mny, wred[w][1]); mnz = fminf(mnz, wred[w][2]);
        mxx = fmaxf(mxx, wred[w][3]); mxy = fmaxf(mxy, wred[w][4]); mxz = fmaxf(mxz, wred[w][5]);
    }
    float sclx = 8.0f / fmaxf(mxx - mnx, 1e-9f);
    float scly = 8.0f / fmaxf(mxy - mny, 1e-9f);
    float sclz = 8.0f / fmaxf(mxz - mnz, 1e-9f);
    int mcode[8];
#pragma unroll
    for (int j = 0; j < 8; ++j) {
        int ux = (int)((lx[j] - mnx) * sclx); ux = ux < 0 ? 0 : (ux > 7 ? 7 : ux);
        int uy = (int)((ly[j] - mny) * scly); uy = uy < 0 ? 0 : (uy > 7 ? 7 : uy);
        int uz = (int)((lz[j] - mnz) * sclz); uz = uz < 0 ? 0 : (uz > 7 ? 7 : uz);
        mcode[j] = spread3(ux) | (spread3(uy) << 1) | (spread3(uz) << 2);
        atomicAdd(&hist[mcode[j]], 1u);
    }
    __syncthreads();
    unsigned v = 0, incl = 0;
    if (t < 512) {
        v = hist[t];
        incl = v;
#pragma unroll
        for (int d = 1; d < 64; d <<= 1) {
            unsigned u = __shfl_up(incl, d);
            if (lane >= d) incl += u;
        }
        if (lane == 63) wsum[wid] = incl;
    }
    __syncthreads();
    if (t < 512) {
        unsigned off = 0;
        for (int w = 0; w < wid; ++w) off += wsum[w];
        starts[t] = off + incl - v;
    }
    __syncthreads();
#pragma unroll
    for (int j = 0; j < 8; ++j) {
        unsigned pos = atomicAdd(&starts[mcode[j]], 1u);
        perm[pos] = (unsigned short)(t * 8 + j);
    }
    __syncthreads();
#pragma unroll
    for (int j = 0; j < 8; ++j) {
        int pos = t * 8 + j;
        int o = perm[pos];
        spx[(long)b * NN + pos] = xb[o];
        spy[(long)b * NN + pos] = xb[NN + o];
        spz[(long)b * NN + pos] = xb[2 * NN + o];
        soi[(long)b * NN + pos] = o;
    }
}

// ---------------- FPS phase 2: iteration loop (256 thr = 4 waves/batch) -------
// Packed-key argmax: key = (bits(dist)<<32) | ~idx; tie -> lowest orig index
// (np.argmax semantics). Each thread owns 32 Morton-contiguous points in
// REGISTERS, split into 4 sub-groups of 8 with cached per-group winner keys.
// Per iteration: conservative bbox lower-bound tests (margin 1e-5 >> rounding)
// skip provably-no-op updates at thread and sub-group granularity; active waves
// DPP-reduce 64 per-thread cached keys; 4 wave winners cross via tiny LDS slots
// (4-slot sequential compare, no second reduce tree). 1 wave/SIMD -> no VALU
// issue contention; 4-wave barrier. Bit-exact: skipped updates satisfy d > dist
// under worst-case rounding; min() over a multiset is order-independent;
// winner coords ride through LDS so the next center needs no memory fetch.
#define OIv(p) ((int)((opk[(p) >> 1] >> (((p) & 1) * 16)) & 0xffffu))

__global__ __launch_bounds__(256)
void fps_iter_kernel(const float* __restrict__ xyz,
                     const float* __restrict__ spx, const float* __restrict__ spy,
                     const float* __restrict__ spz, const int* __restrict__ soi,
                     float* __restrict__ new_xyz,  // [B,S,3]
                     float* __restrict__ out0,     // [B,3,S]
                     float* __restrict__ out2)     // [B,S] (float indices)
{
    int b = blockIdx.x, t = threadIdx.x;
    int lane = t & 63, wid = t >> 6;
    const float* xb = xyz + (long)b * 3 * NN;
    long base = (long)b * NN + (long)t * 32;

    float px[32], py[32], pz[32], dist[32];
    unsigned opk[16];
#pragma unroll
    for (int q = 0; q < 8; ++q) {
        float4 v4x = *(const float4*)(spx + base + q * 4);
        float4 v4y = *(const float4*)(spy + base + q * 4);
        float4 v4z = *(const float4*)(spz + base + q * 4);
        px[q*4+0] = v4x.x; px[q*4+1] = v4x.y; px[q*4+2] = v4x.z; px[q*4+3] = v4x.w;
        py[q*4+0] = v4y.x; py[q*4+1] = v4y.y; py[q*4+2] = v4y.z; py[q*4+3] = v4y.w;
        pz[q*4+0] = v4z.x; pz[q*4+1] = v4z.y; pz[q*4+2] = v4z.z; pz[q*4+3] = v4z.w;
    }
#pragma unroll
    for (int j = 0; j < 16; ++j) {
        int o0 = soi[base + 2 * j], o1 = soi[base + 2 * j + 1];
        opk[j] = (unsigned)o0 | ((unsigned)o1 << 16);
    }
#pragma unroll
    for (int j = 0; j < 32; ++j) dist[j] = 1e10f;

    // sub-group bboxes (4 x 8 points) + thread bbox
    float sx0[4], sx1[4], sy0[4], sy1[4], sz0[4], sz1[4];
#pragma unroll
    for (int g = 0; g < 4; ++g) {
        float a0 = 3.4e38f, a1 = -3.4e38f, b0_ = 3.4e38f, b1_ = -3.4e38f, c0 = 3.4e38f, c1 = -3.4e38f;
#pragma unroll
        for (int j = 0; j < 8; ++j) {
            const int p = g * 8 + j;
            a0 = fminf(a0, px[p]); a1 = fmaxf(a1, px[p]);
            b0_ = fminf(b0_, py[p]); b1_ = fmaxf(b1_, py[p]);
            c0 = fminf(c0, pz[p]); c1 = fmaxf(c1, pz[p]);
        }
        sx0[g] = a0; sx1[g] = a1; sy0[g] = b0_; sy1[g] = b1_; sz0[g] = c0; sz1[g] = c1;
    }
    float tbx0 = fminf(fminf(sx0[0], sx0[1]), fminf(sx0[2], sx0[3]));
    float tbx1 = fmaxf(fmaxf(sx1[0], sx1[1]), fmaxf(sx1[2], sx1[3]));
    float tby0 = fminf(fminf(sy0[0], sy0[1]), fminf(sy0[2], sy0[3]));
    float tby1 = fmaxf(fmaxf(sy1[0], sy1[1]), fmaxf(sy1[2], sy1[3]));
    float tbz0 = fminf(fminf(sz0[0], sz0[1]), fminf(sz0[2], sz0[3]));
    float tbz1 = fmaxf(fmaxf(sz1[0], sz1[1]), fmaxf(sz1[2], sz1[3]));

    // per-group cached winners, per-thread cached winner
    unsigned gkh[4], gkl[4];
    float gvx[4], gvy[4], gvz[4];
#pragma unroll
    for (int g = 0; g < 4; ++g) { gkh[g] = __float_as_uint(1e10f); gkl[g] = 0u; gvx[g] = 0.f; gvy[g] = 0.f; gvz[g] = 0.f; }
    unsigned kh = __float_as_uint(1e10f), kl = 0u;
    float bx = 0.f, by = 0.f, bz = 0.f;
    bool iswin = false;

    __shared__ unsigned long long skey[2][4];
    __shared__ float4 sval[2][4];
    __shared__ unsigned short pick[SS];          // 4 KB

    if (t == 0) pick[0] = 0;
    float cx = xb[0], cy = xb[NN], cz = xb[2 * NN];   // point 0

#define DPPK(CTRL) { \
    unsigned ol = (unsigned)__builtin_amdgcn_update_dpp(0, (int)rl, CTRL, 0xf, 0xf, true); \
    unsigned oh = (unsigned)__builtin_amdgcn_update_dpp(0, (int)rh, CTRL, 0xf, 0xf, true); \
    bool tk = (oh > rh) || (oh == rh && ol > rl); \
    rh = tk ? oh : rh; rl = tk ? ol : rl; \
}

    for (int i = 1; i < SS; ++i) {
        float gx = fmaxf(fmaxf(tbx0 - cx, cx - tbx1), 0.f);
        float gy = fmaxf(fmaxf(tby0 - cy, cy - tby1), 0.f);
        float gz = fmaxf(fmaxf(tbz0 - cz, cz - tbz1), 0.f);
        float lb = gx * gx + gy * gy + gz * gz;
        bool act = lb <= __uint_as_float(kh) * 1.00001f;
        if (__any((int)act)) {
            if (act) {
#pragma unroll
                for (int g = 0; g < 4; ++g) {
                    float hx = fmaxf(fmaxf(sx0[g] - cx, cx - sx1[g]), 0.f);
                    float hy = fmaxf(fmaxf(sy0[g] - cy, cy - sy1[g]), 0.f);
                    float hz = fmaxf(fmaxf(sz0[g] - cz, cz - sz1[g]), 0.f);
                    float lbg = hx * hx + hy * hy + hz * hz;
                    if (lbg <= __uint_as_float(gkh[g]) * 1.00001f) {
                        float bv = -1.f; int bi = 0x7fffffff;
                        float nx_ = 0.f, ny_ = 0.f, nz_ = 0.f;
#pragma unroll
                        for (int j = 0; j < 8; ++j) {
                            const int p = g * 8 + j;
                            float dx = __fsub_rn(px[p], cx), dy = __fsub_rn(py[p], cy), dz = __fsub_rn(pz[p], cz);
                            float d = sq3(dx, dy, dz);
                            float nd = fminf(dist[p], d);
                            dist[p] = nd;
                            int po = OIv(p);
                            bool bet = (nd > bv) || (nd == bv && po < bi);
                            if (bet) { bv = nd; bi = po; nx_ = px[p]; ny_ = py[p]; nz_ = pz[p]; }
                        }
                        gkh[g] = __float_as_uint(bv); gkl[g] = ~(unsigned)bi;
                        gvx[g] = nx_; gvy[g] = ny_; gvz[g] = nz_;
                    }
                }
                kh = gkh[0]; kl = gkl[0]; bx = gvx[0]; by = gvy[0]; bz = gvz[0];
#pragma unroll
                for (int g = 1; g < 4; ++g) {
                    bool bet = (gkh[g] > kh) || (gkh[g] == kh && gkl[g] > kl);
                    if (bet) { kh = gkh[g]; kl = gkl[g]; bx = gvx[g]; by = gvy[g]; bz = gvz[g]; }
                }
            }
            // wave max over 64 cached per-thread keys (DPP, result in lane 63)
            unsigned rl = kl, rh = kh;
            DPPK(0x111) DPPK(0x112) DPPK(0x114) DPPK(0x118) DPPK(0x142) DPPK(0x143)
            unsigned wl = (unsigned)__builtin_amdgcn_readlane((int)rl, 63);
            unsigned wh = (unsigned)__builtin_amdgcn_readlane((int)rh, 63);
            iswin = (kl == wl) && (kh == wh);   // keys unique -> exactly one winner lane
        }
        int buf = i & 1;
        if (iswin) {
            skey[buf][wid] = ((unsigned long long)kh << 32) | kl;
            sval[buf][wid] = make_float4(bx, by, bz, 0.f);
        }
        __syncthreads();
        unsigned long long k0 = skey[buf][0], k1 = skey[buf][1], k2 = skey[buf][2], k3 = skey[buf][3];
        float4 v0 = sval[buf][0], v1 = sval[buf][1], v2 = sval[buf][2], v3 = sval[buf][3];
        unsigned long long kb = k0; float wx = v0.x, wy = v0.y, wz = v0.z;
        if (k1 > kb) { kb = k1; wx = v1.x; wy = v1.y; wz = v1.z; }
        if (k2 > kb) { kb = k2; wx = v2.x; wy = v2.y; wz = v2.z; }
        if (k3 > kb) { kb = k3; wx = v3.x; wy = v3.y; wz = v3.z; }
        cx = wx; cy = wy; cz = wz;
        if (t == 0) pick[i] = (unsigned short)(~(unsigned)(kb & 0xffffffffull));
    }
#undef DPPK
    __syncthreads();
    for (int i = t; i < SS; i += 256) {
        int n = pick[i];
        float x = xb[n], y = xb[NN + n], z = xb[2 * NN + n];
        new_xyz[((long)b * SS + i) * 3 + 0] = x;
        new_xyz[((long)b * SS + i) * 3 + 1] = y;
        new_xyz[((long)b * SS + i) * 3 + 2] = z;
        out0[(long)b * 3 * SS + 0 * SS + i] = x;
        out0[(long)b * 3 * SS + 1 * SS + i] = y;
        out0[(long)b * 3 * SS + 2 * SS + i] = z;
        out2[b * SS + i] = (float)n;
    }
}

// ---------------- KNN: one wave per center -------------------
__global__ __launch_bounds__(256)
void knn_kernel(const float* __restrict__ xyz,      // [B,3,N]
                const float* __restrict__ new_xyz,  // [B,S,3]
                int* __restrict__ knn_idx)          // [B*S,16]
{
    int gwave = (blockIdx.x * 256 + threadIdx.x) >> 6;
    int lane = threadIdx.x & 63;
    int wid = threadIdx.x >> 6;
    if (gwave >= BB * SS) return;
    int b = gwave / SS;
    const float* xb = xyz + (long)b * 3 * NN;
    float nx = new_xyz[(long)gwave * 3 + 0];
    float ny = new_xyz[(long)gwave * 3 + 1];
    float nz = new_xyz[(long)gwave * 3 + 2];
    float snew = sq3(nx, ny, nz);
    float kd[16]; int ki[16];
#pragma unroll
    for (int j = 0; j < 16; ++j) { kd[j] = 3.4e38f; ki[j] = 0x7fffffff; }
    for (int tix = 0; tix < NN / 64; ++tix) {
        int n = tix * 64 + lane;
        float qx = xb[n], qy = xb[NN + n], qz = xb[2 * NN + n];
        float sx = sq3(qx, qy, qz);
        float dot = __fadd_rn(__fadd_rn(__fmul_rn(nx, qx), __fmul_rn(ny, qy)), __fmul_rn(nz, qz));
        float d = __fsub_rn(__fadd_rn(snew, sx), __fmul_rn(2.0f, dot));
        if (d < kd[15] || (d == kd[15] && n < ki[15])) {
            kd[15] = d; ki[15] = n;
#pragma unroll
            for (int j = 15; j >= 1; --j) {
                bool sw = kd[j] < kd[j - 1] || (kd[j] == kd[j - 1] && ki[j] < ki[j - 1]);
                if (sw) {
                    float td = kd[j]; kd[j] = kd[j - 1]; kd[j - 1] = td;
                    int ti = ki[j]; ki[j] = ki[j - 1]; ki[j - 1] = ti;
                }
            }
        }
    }
    // merge 64 sorted 16-lists via LDS + 16 extraction rounds
    __shared__ float ld[4][64][17];
    __shared__ int   li[4][64][17];
#pragma unroll
    for (int j = 0; j < 16; ++j) { ld[wid][lane][j] = kd[j]; li[wid][lane][j] = ki[j]; }
    int h = 0, myres = 0;
#pragma unroll
    for (int r = 0; r < 16; ++r) {
        float cd = (h < 16) ? ld[wid][lane][h] : 3.4e38f;
        int   ci = (h < 16) ? li[wid][lane][h] : 0x7fffffff;
        float bd = cd; int bi = ci;
#pragma unroll
        for (int off = 1; off < 64; off <<= 1) {
            float od = __shfl_xor(bd, off); int oi = __shfl_xor(bi, off);
            if (od < bd || (od == bd && oi < bi)) { bd = od; bi = oi; }
        }
        if (bd == cd && bi == ci) h++;
        if (lane == r) myres = bi;
    }
    if (lane < 16) knn_idx[(long)gwave * 16 + lane] = myres;
}

// ---------------- BN0/BN1 stats pass -------------------
__global__ __launch_bounds__(256)
void mlp01_stats_kernel(const float* __restrict__ points,   // [B,64,N]
                        const float* __restrict__ xyz,      // [B,3,N]
                        const float* __restrict__ new_xyz,  // [B,S,3]
                        const int* __restrict__ knn_idx,    // [B*S,16]
                        const float* __restrict__ W0, const float* __restrict__ b0,
                        const float* __restrict__ W1, const float* __restrict__ b1,
                        float* __restrict__ sums)           // [4][64]
{
    int wid = threadIdx.x >> 6, lane = threadIdx.x & 63;
    long base = (long)blockIdx.x * 64 + wid * 16;
    float a0 = 0, q0 = 0, a1 = 0, q1 = 0;
    for (int it = 0; it < 16; ++it) {
        long pos = base + it;
        int bs = (int)(pos >> 4);
        int b = bs >> 11;
        int n = knn_idx[pos];
        float gp = points[(long)b * INCH * NN + (long)lane * NN + n];
        float x0 = b0[lane];
#pragma unroll
        for (int d = 0; d < 64; ++d)
            x0 = fmaf(__shfl(gp, d), W0[d * 64 + lane], x0);
        float nx = new_xyz[(long)bs * 3], ny = new_xyz[(long)bs * 3 + 1], nz = new_xyz[(long)bs * 3 + 2];
        const float* xb = xyz + (long)b * 3 * NN;
        float qx = xb[n], qy = xb[NN + n], qz = xb[2 * NN + n];
        float c9[9] = {nx, ny, nz, qx, qy, qz, qx - nx, qy - ny, qz - nz};
        float x1 = b1[lane];
#pragma unroll
        for (int j = 0; j < 9; ++j) x1 = fmaf(c9[j], W1[j * 64 + lane], x1);
        a0 += x0; q0 += x0 * x0; a1 += x1; q1 += x1 * x1;
    }
    __shared__ float red[4][4][64];
    red[0][wid][lane] = a0; red[1][wid][lane] = q0; red[2][wid][lane] = a1; red[3][wid][lane] = q1;
    __syncthreads();
    if (threadIdx.x < 64) {
#pragma unroll
        for (int arr = 0; arr < 4; ++arr) {
            float v = red[arr][0][lane] + red[arr][1][lane] + red[arr][2][lane] + red[arr][3][lane];
            atomicAdd(&sums[arr * 64 + lane], v);
        }
    }
}

__global__ void bn01_finalize(const float* __restrict__ sums,
                              const float* __restrict__ g0, const float* __restrict__ be0,
                              const float* __restrict__ g1, const float* __restrict__ be1,
                              float* __restrict__ ss01)
{
    int c = threadIdx.x;  // 64
    float inv = 1.0f / (float)(BB * SS * KK);
    float m0 = sums[c] * inv,        v0 = sums[64 + c] * inv - m0 * m0;
    float m1 = sums[128 + c] * inv,  v1 = sums[192 + c] * inv - m1 * m1;
    float sc0 = g0[c] / sqrtf(v0 + EPSF);
    float sc1 = g1[c] / sqrtf(v1 + EPSF);
    ss01[c] = sc0;        ss01[64 + c] = be0[c] - m0 * sc0;
    ss01[128 + c] = sc1;  ss01[192 + c] = be1[c] - m1 * sc1;
}

// ---------------- per-center fused: lse1 -> scores -> softmax -> features1 ----------
__global__ __launch_bounds__(256)
void center_kernel(const float* __restrict__ points, const float* __restrict__ xyz,
                   const float* __restrict__ new_xyz, const int* __restrict__ knn_idx,
                   const float* __restrict__ W0, const float* __restrict__ b0,
                   const float* __restrict__ W1, const float* __restrict__ b1,
                   const float* __restrict__ ss01, const float* __restrict__ Ws,
                   float* __restrict__ features1)   // [B*S,128]
{
    int bs = blockIdx.x;
    int b = bs >> 11;
    int wid = threadIdx.x >> 6, lane = threadIdx.x & 63;
    __shared__ float lse[KK][OUTC];
    __shared__ float sraw[KK][OUTC];
    float sc0 = ss01[lane], sh0 = ss01[64 + lane], sc1 = ss01[128 + lane], sh1 = ss01[192 + lane];
    float nx = new_xyz[(long)bs * 3], ny = new_xyz[(long)bs * 3 + 1], nz = new_xyz[(long)bs * 3 + 2];
    const float* xb = xyz + (long)b * 3 * NN;
#pragma unroll
    for (int kk = 0; kk < 4; ++kk) {
        int k = wid * 4 + kk;
        int n = knn_idx[(long)bs * 16 + k];
        float gp = points[(long)b * INCH * NN + (long)lane * NN + n];
        float x0 = b0[lane];
#pragma unroll
        for (int d = 0; d < 64; ++d)
            x0 = fmaf(__shfl(gp, d), W0[d * 64 + lane], x0);
        float qx = xb[n], qy = xb[NN + n], qz = xb[2 * NN + n];
        float c9[9] = {nx, ny, nz, qx, qy, qz, qx - nx, qy - ny, qz - nz};
        float x1 = b1[lane];
#pragma unroll
        for (int j = 0; j < 9; ++j) x1 = fmaf(c9[j], W1[j * 64 + lane], x1);
        x0 = leaky_f(x0 * sc0 + sh0);
        x1 = leaky_f(x1 * sc1 + sh1);
        lse[k][lane] = x1;        // channels 0..63 : lse_part (W1 path)
        lse[k][64 + lane] = x0;   // channels 64..127 : new_points (W0 path)
    }
    __syncthreads();
    // scores raw: sraw[k][d] = sum_c lse[k][c]*Ws[c][d]
    int d = threadIdx.x & 127;
    int kg = threadIdx.x >> 7;   // 0..1 -> 8 k's each
    float acc[8];
#pragma unroll
    for (int i = 0; i < 8; ++i) acc[i] = 0.f;
    for (int c = 0; c < OUTC; ++c) {
        float w = Ws[c * OUTC + d];
#pragma unroll
        for (int i = 0; i < 8; ++i) acc[i] = fmaf(lse[kg * 8 + i][c], w, acc[i]);
    }
#pragma unroll
    for (int i = 0; i < 8; ++i) sraw[kg * 8 + i][d] = leaky_f(acc[i]);
    __syncthreads();
    if (threadIdx.x < OUTC) {
        int dd = threadIdx.x;
        float vals[KK];
        float mx = -3.4e38f;
#pragma unroll
        for (int k = 0; k < KK; ++k) { vals[k] = sraw[k][dd]; mx = fmaxf(mx, vals[k]); }
        float sum = 0.f;
#pragma unroll
        for (int k = 0; k < KK; ++k) { vals[k] = __expf(vals[k] - mx); sum += vals[k]; }
        float invs = 1.0f / sum;
        float feat = 0.f;
#pragma unroll
        for (int k = 0; k < KK; ++k) feat = fmaf(vals[k] * invs, lse[k][dd], feat);
        features1[(long)bs * OUTC + dd] = feat;
    }
}

// ---------------- mlp2 GEMM + stats -------------------
__global__ __launch_bounds__(256)
void mlp2_kernel(const float* __restrict__ features1,  // [B*S,128]
                 const float* __restrict__ W2, const float* __restrict__ b2,
                 float* __restrict__ x2,               // [B*S,128]
                 float* __restrict__ sums2)            // [2][128]
{
    int p0 = blockIdx.x * 16;
    __shared__ float f[16][OUTC];
    for (int i = threadIdx.x; i < 16 * OUTC; i += 256)
        f[i >> 7][i & 127] = features1[(long)p0 * OUTC + i];
    __syncthreads();
    int d = threadIdx.x & 127;
    int g = threadIdx.x >> 7;
    float acc[8];
#pragma unroll
    for (int i = 0; i < 8; ++i) acc[i] = b2[d];
    for (int c = 0; c < OUTC; ++c) {
        float w = W2[c * OUTC + d];
#pragma unroll
        for (int i = 0; i < 8; ++i) acc[i] = fmaf(f[g * 8 + i][c], w, acc[i]);
    }
    float s = 0.f, q = 0.f;
#pragma unroll
    for (int i = 0; i < 8; ++i) {
        x2[(long)(p0 + g * 8 + i) * OUTC + d] = acc[i];
        s += acc[i]; q += acc[i] * acc[i];
    }
    __shared__ float rs[2][2][OUTC];
    rs[0][g][d] = s; rs[1][g][d] = q;
    __syncthreads();
    if (threadIdx.x < OUTC) {
        atomicAdd(&sums2[d],        rs[0][0][d] + rs[0][1][d]);
        atomicAdd(&sums2[OUTC + d], rs[1][0][d] + rs[1][1][d]);
    }
}

__global__ void bn2_finalize(const float* __restrict__ sums2,
                             const float* __restrict__ g2, const float* __restrict__ be2,
                             float* __restrict__ ss2)
{
    int c = threadIdx.x;  // 128
    float inv = 1.0f / (float)(BB * SS);
    float m = sums2[c] * inv, v = sums2[OUTC + c] * inv - m * m;
    float sc = g2[c] / sqrtf(v + EPSF);
    ss2[c] = sc; ss2[OUTC + c] = be2[c] - m * sc;
}

__global__ __launch_bounds__(256)
void out1_kernel(const float* __restrict__ x2, const float* __restrict__ ss2,
                 float* __restrict__ out1)   // [B,128,S]
{
    int bc = blockIdx.x;
    int b = bc >> 7, c = bc & 127;
    float sc = ss2[c], sh = ss2[OUTC + c];
    for (int s = threadIdx.x; s < SS; s += 256) {
        float v = x2[((long)(b * SS + s)) * OUTC + c] * sc + sh;
        out1[(long)b * OUTC * SS + (long)c * SS + s] = leaky_f(v);
    }
}

extern "C" void kernel_launch(void* const* d_in, const int* in_sizes, int n_in,
                              void* d_out, int out_size, void* d_ws, size_t ws_size,
                              hipStream_t stream)
{
    const float* xyz    = (const float*)d_in[0];
    const float* points = (const float*)d_in[1];
    const float* W0  = (const float*)d_in[2];
    const float* b0  = (const float*)d_in[3];
    const float* g0  = (const float*)d_in[4];
    const float* be0 = (const float*)d_in[5];
    const float* W1  = (const float*)d_in[6];
    const float* b1  = (const float*)d_in[7];
    const float* g1  = (const float*)d_in[8];
    const float* be1 = (const float*)d_in[9];
    const float* Ws  = (const float*)d_in[10];
    const float* W2  = (const float*)d_in[11];
    const float* b2  = (const float*)d_in[12];
    const float* g2  = (const float*)d_in[13];
    const float* be2 = (const float*)d_in[14];

    char* ws = (char*)d_ws;
    float* nxyz   = (float*)(ws + 32768);        // 98304 B
    int*   knn_i  = (int*)(ws + 131072);         // 524288 B
    float* sums01 = (float*)(ws + 655360);       // 1024 B
    float* sums2  = (float*)(ws + 656384);       // 1024 B
    float* ss01   = (float*)(ws + 657408);       // 1024 B
    float* ss2    = (float*)(ws + 658432);       // 1024 B
    float* feat1  = (float*)(ws + 659456);       // 4 MB
    float* x2     = (float*)(ws + 659456 + 4194304); // 4 MB

    // sorted-point scratch lives INSIDE feat1's 4 MB (dead until center_kernel,
    // and fps consumes it before center_kernel runs): 4 arrays x 128 KB.
    float* spx = feat1;
    float* spy = spx + (long)BB * NN;
    float* spz = spy + (long)BB * NN;
    int*   soi = (int*)(spz + (long)BB * NN);

    float* out0 = (float*)d_out;                       // [B,3,S]
    float* out1 = out0 + (long)BB * 3 * SS;            // [B,128,S]
    float* out2 = out1 + (long)BB * OUTC * SS;         // [B,S] float idx

    hipMemsetAsync(sums01, 0, 2048, stream);  // zero sums01 + sums2 (contiguous)

    fps_sort_kernel<<<BB, 1024, 0, stream>>>(xyz, spx, spy, spz, soi);
    fps_iter_kernel<<<BB, 256, 0, stream>>>(xyz, spx, spy, spz, soi, nxyz, out0, out2);
    knn_kernel<<<(BB * SS) / 4, 256, 0, stream>>>(xyz, nxyz, knn_i);
    mlp01_stats_kernel<<<2048, 256, 0, stream>>>(points, xyz, nxyz, knn_i, W0, b0, W1, b1, sums01);
    bn01_finalize<<<1, 64, 0, stream>>>(sums01, g0, be0, g1, be1, ss01);
    center_kernel<<<BB * SS, 256, 0, stream>>>(points, xyz, nxyz, knn_i, W0, b0, W1, b1, ss01, Ws, feat1);
    mlp2_kernel<<<(BB * SS) / 16, 256, 0, stream>>>(feat1, W2, b2, x2, sums2);
    bn2_finalize<<<1, 128, 0, stream>>>(sums2, g2, be2, ss2);
    out1_kernel<<<BB * OUTC, 256, 0, stream>>>(x2, ss2, out1);
}

// Round 4
// 3570.718 us; speedup vs baseline: 2.1937x; 2.1937x over previous
//
#include <hip/hip_runtime.h>

#define BB 4
#define NN 8192
#define SS 2048
#define KK 16
#define INCH 64
#define HH 64
#define OUTC 128
#define LEAKY_A 0.1f
#define EPSF 1e-5f

__device__ __forceinline__ float sq3(float a, float b, float c) {
    // strict IEEE ((a*a + b*b) + c*c) to match numpy reduction order, no FMA contraction
    return __fadd_rn(__fadd_rn(__fmul_rn(a, a), __fmul_rn(b, b)), __fmul_rn(c, c));
}

__device__ __forceinline__ float leaky_f(float x) { return x >= 0.f ? x : LEAKY_A * x; }

__device__ __forceinline__ int spread3(int v) {
    return (v & 1) | ((v & 2) << 2) | ((v & 4) << 4);
}

// ---------------- FPS: one block (1024 thr) per batch -------------------
// Packed-key argmax: key = (bits(dist)<<32) | ~idx. dist>=0 so float bits are
// order-monotone; ~idx breaks ties toward the lowest index (np.argmax semantics).
// Morton counting-sort prologue gives each thread 8 spatially-tight points;
// per-THREAD conservative bbox lower-bound test (margin 1e-5 >> rounding) skips
// provably-no-op updates. Active waves DPP-reduce (VALU-rate) their 64 cached
// keys; winner lane caches coords and writes {key,coords} to its wave slot.
// Cross-wave: key-only DPP row-reduce over the 16 slots, ballot+ctz finds the
// winning slot, one broadcast LDS float4 read yields the next center's coords
// -> NO global memory on the sequential path. Bit-exact vs reference: skipped
// updates satisfy d > dist under worst-case rounding; min() over a multiset is
// order-independent; tie-breaks carried in packed keys (unique per point; DPP
// bound_ctrl zero-fill (0,0) never beats a real key since real low-word ~idx
// is large).
__global__ __launch_bounds__(1024)
void fps_kernel(const float* __restrict__ xyz,   // [B,3,N]
                int* __restrict__ fps_idx,       // [B,S]
                float* __restrict__ new_xyz,     // [B,S,3]
                float* __restrict__ out0,        // [B,3,S]
                float* __restrict__ out2)        // [B,S] (float indices)
{
    int b = blockIdx.x, t = threadIdx.x;
    int lane = t & 63, wid = t >> 6;
    const float* xb = xyz + (long)b * 3 * NN;

    __shared__ unsigned short perm[NN];          // 16 KB
    __shared__ unsigned int hist[512];           // 2 KB
    __shared__ unsigned int starts[512];         // 2 KB
    __shared__ unsigned int wsum[8];
    __shared__ float wred[16][6];
    __shared__ unsigned long long skey[2][16];   // per-wave winner key
    __shared__ float4 sval[2][16];               // per-wave winner coords

    // ---- prologue: load, block bbox, morton codes ----
    float lx[8], ly[8], lz[8];
    float mnx = 3.4e38f, mny = 3.4e38f, mnz = 3.4e38f;
    float mxx = -3.4e38f, mxy = -3.4e38f, mxz = -3.4e38f;
#pragma unroll
    for (int j = 0; j < 8; ++j) {
        int n = t * 8 + j;
        lx[j] = xb[n]; ly[j] = xb[NN + n]; lz[j] = xb[2 * NN + n];
        mnx = fminf(mnx, lx[j]); mxx = fmaxf(mxx, lx[j]);
        mny = fminf(mny, ly[j]); mxy = fmaxf(mxy, ly[j]);
        mnz = fminf(mnz, lz[j]); mxz = fmaxf(mxz, lz[j]);
    }
#pragma unroll
    for (int off = 1; off < 64; off <<= 1) {
        mnx = fminf(mnx, __shfl_xor(mnx, off)); mxx = fmaxf(mxx, __shfl_xor(mxx, off));
        mny = fminf(mny, __shfl_xor(mny, off)); mxy = fmaxf(mxy, __shfl_xor(mxy, off));
        mnz = fminf(mnz, __shfl_xor(mnz, off)); mxz = fmaxf(mxz, __shfl_xor(mxz, off));
    }
    if (lane == 0) {
        wred[wid][0] = mnx; wred[wid][1] = mny; wred[wid][2] = mnz;
        wred[wid][3] = mxx; wred[wid][4] = mxy; wred[wid][5] = mxz;
    }
    if (t < 512) hist[t] = 0;
    __syncthreads();
    mnx = wred[0][0]; mny = wred[0][1]; mnz = wred[0][2];
    mxx = wred[0][3]; mxy = wred[0][4]; mxz = wred[0][5];
#pragma unroll
    for (int w = 1; w < 16; ++w) {
        mnx = fminf(mnx, wred[w][0]); mny = fminf(mny, wred[w][1]); mnz = fminf(mnz, wred[w][2]);
        mxx = fmaxf(mxx, wred[w][3]); mxy = fmaxf(mxy, wred[w][4]); mxz = fmaxf(mxz, wred[w][5]);
    }
    float sclx = 8.0f / fmaxf(mxx - mnx, 1e-9f);
    float scly = 8.0f / fmaxf(mxy - mny, 1e-9f);
    float sclz = 8.0f / fmaxf(mxz - mnz, 1e-9f);
    int mcode[8];
#pragma unroll
    for (int j = 0; j < 8; ++j) {
        int ux = (int)((lx[j] - mnx) * sclx); ux = ux < 0 ? 0 : (ux > 7 ? 7 : ux);
        int uy = (int)((ly[j] - mny) * scly); uy = uy < 0 ? 0 : (uy > 7 ? 7 : uy);
        int uz = (int)((lz[j] - mnz) * sclz); uz = uz < 0 ? 0 : (uz > 7 ? 7 : uz);
        mcode[j] = spread3(ux) | (spread3(uy) << 1) | (spread3(uz) << 2);
        atomicAdd(&hist[mcode[j]], 1u);
    }
    __syncthreads();
    // exclusive scan over 512 bins (waves 0..7)
    unsigned v = 0, incl = 0;
    if (t < 512) {
        v = hist[t];
        incl = v;
#pragma unroll
        for (int d = 1; d < 64; d <<= 1) {
            unsigned u = __shfl_up(incl, d);
            if (lane >= d) incl += u;
        }
        if (lane == 63) wsum[wid] = incl;
    }
    __syncthreads();
    if (t < 512) {
        unsigned off = 0;
        for (int w = 0; w < wid; ++w) off += wsum[w];
        starts[t] = off + incl - v;
    }
    __syncthreads();
#pragma unroll
    for (int j = 0; j < 8; ++j) {
        unsigned pos = atomicAdd(&starts[mcode[j]], 1u);
        perm[pos] = (unsigned short)(t * 8 + j);
    }
    __syncthreads();

    // ---- gather spatially-sorted points, sort each thread's 8 by orig idx ----
    float px[8], py[8], pz[8], dist[8];
    int oi[8];
#pragma unroll
    for (int j = 0; j < 8; ++j) {
        int o = perm[t * 8 + j];
        oi[j] = o;
        px[j] = xb[o]; py[j] = xb[NN + o]; pz[j] = xb[2 * NN + o];
        dist[j] = 1e10f;
    }
#define CSWAP(a, b) { if (oi[a] > oi[b]) { int ti = oi[a]; oi[a] = oi[b]; oi[b] = ti; \
    float tf; tf = px[a]; px[a] = px[b]; px[b] = tf; \
    tf = py[a]; py[a] = py[b]; py[b] = tf; \
    tf = pz[a]; pz[a] = pz[b]; pz[b] = tf; } }
    CSWAP(0,1) CSWAP(2,3) CSWAP(4,5) CSWAP(6,7)
    CSWAP(0,2) CSWAP(1,3) CSWAP(4,6) CSWAP(5,7)
    CSWAP(1,2) CSWAP(5,6)
    CSWAP(0,4) CSWAP(1,5) CSWAP(2,6) CSWAP(3,7)
    CSWAP(2,4) CSWAP(3,5)
    CSWAP(1,2) CSWAP(3,4) CSWAP(5,6)
#undef CSWAP
    // per-thread bbox of its 8 points
    float tbx0 = 3.4e38f, tby0 = 3.4e38f, tbz0 = 3.4e38f;
    float tbx1 = -3.4e38f, tby1 = -3.4e38f, tbz1 = -3.4e38f;
#pragma unroll
    for (int j = 0; j < 8; ++j) {
        tbx0 = fminf(tbx0, px[j]); tbx1 = fmaxf(tbx1, px[j]);
        tby0 = fminf(tby0, py[j]); tby1 = fmaxf(tby1, py[j]);
        tbz0 = fminf(tbz0, pz[j]); tbz1 = fmaxf(tbz1, pz[j]);
    }

    // persistent per-thread state: packed key (kh=dist bits, kl=~idx), coords
    unsigned kh = __float_as_uint(1e10f), kl = 0u;
    float bx = 0.f, by = 0.f, bz = 0.f;
    bool iswin = false;

    if (t == 0) fps_idx[b * SS] = 0;
    float cx = xb[0], cy = xb[NN], cz = xb[2 * NN];   // point 0

// max-reduce step on (rh,rl) via DPP (bound_ctrl zero-fill never wins)
#define DPPK(CTRL) { \
    unsigned ol = (unsigned)__builtin_amdgcn_update_dpp(0, (int)rl, CTRL, 0xf, 0xf, true); \
    unsigned oh = (unsigned)__builtin_amdgcn_update_dpp(0, (int)rh, CTRL, 0xf, 0xf, true); \
    bool tk = (oh > rh) || (oh == rh && ol > rl); \
    rh = tk ? oh : rh; rl = tk ? ol : rl; \
}

    for (int i = 1; i < SS; ++i) {
        // conservative lower bound of squared distance from c to this thread's bbox
        float gx = fmaxf(fmaxf(tbx0 - cx, cx - tbx1), 0.f);
        float gy = fmaxf(fmaxf(tby0 - cy, cy - tby1), 0.f);
        float gz = fmaxf(fmaxf(tbz0 - cz, cz - tbz1), 0.f);
        float lb = gx * gx + gy * gy + gz * gz;
        bool thr_act = lb <= __uint_as_float(kh) * 1.00001f;
        if (__any((int)thr_act)) {
            if (thr_act) {
                float bv = -1.f; int bi = 0; float nbx = 0.f, nby = 0.f, nbz = 0.f;
#pragma unroll
                for (int j = 0; j < 8; ++j) {
                    float dx = __fsub_rn(px[j], cx), dy = __fsub_rn(py[j], cy), dz = __fsub_rn(pz[j], cz);
                    float d = sq3(dx, dy, dz);
                    float nd = fminf(dist[j], d);
                    dist[j] = nd;
                    if (nd > bv) { bv = nd; bi = oi[j]; nbx = px[j]; nby = py[j]; nbz = pz[j]; }
                }
                kh = __float_as_uint(bv); kl = ~(unsigned)bi;
                bx = nbx; by = nby; bz = nbz;
            }
            // wave max over 64 cached per-thread keys (DPP, result in lane 63)
            unsigned rl = kl, rh = kh;
            DPPK(0x111) DPPK(0x112) DPPK(0x114) DPPK(0x118) DPPK(0x142) DPPK(0x143)
            unsigned wl = (unsigned)__builtin_amdgcn_readlane((int)rl, 63);
            unsigned wh = (unsigned)__builtin_amdgcn_readlane((int)rh, 63);
            iswin = (kl == wl) && (kh == wh);   // keys unique -> exactly one winner lane
        }
        int buf = i & 1;
        if (iswin) {
            skey[buf][wid] = ((unsigned long long)kh << 32) | kl;
            sval[buf][wid] = make_float4(bx, by, bz, 0.f);
        }
        __syncthreads();
        // cross-wave: key-only DPP row-reduce over 16 slots (rows identical)
        unsigned long long myslot = skey[buf][lane & 15];
        unsigned xl = (unsigned)myslot, xh = (unsigned)(myslot >> 32);
        {
            unsigned rl = xl, rh = xh;
            DPPK(0x111) DPPK(0x112) DPPK(0x114) DPPK(0x118)
            unsigned wl = (unsigned)__builtin_amdgcn_readlane((int)rl, 15);
            unsigned wh = (unsigned)__builtin_amdgcn_readlane((int)rh, 15);
            bool slotwin = (lane < 16) && (xl == wl) && (xh == wh);
            unsigned long long mask = __ballot((int)slotwin);
            int widx = (int)__builtin_ctzll(mask);   // unique winning slot
            float4 wv = sval[buf][widx];             // broadcast LDS read
            cx = wv.x; cy = wv.y; cz = wv.z;
            if (t == 0) fps_idx[b * SS + i] = (int)(~wl);
        }
    }
#undef DPPK
    __syncthreads();
    for (int i = t; i < SS; i += 1024) {
        int n = fps_idx[b * SS + i];
        float x = xb[n], y = xb[NN + n], z = xb[2 * NN + n];
        new_xyz[((long)b * SS + i) * 3 + 0] = x;
        new_xyz[((long)b * SS + i) * 3 + 1] = y;
        new_xyz[((long)b * SS + i) * 3 + 2] = z;
        out0[(long)b * 3 * SS + 0 * SS + i] = x;
        out0[(long)b * 3 * SS + 1 * SS + i] = y;
        out0[(long)b * 3 * SS + 2 * SS + i] = z;
        out2[b * SS + i] = (float)n;
    }
}

// ---------------- KNN: one wave per center -------------------
__global__ __launch_bounds__(256)
void knn_kernel(const float* __restrict__ xyz,      // [B,3,N]
                const float* __restrict__ new_xyz,  // [B,S,3]
                int* __restrict__ knn_idx)          // [B*S,16]
{
    int gwave = (blockIdx.x * 256 + threadIdx.x) >> 6;
    int lane = threadIdx.x & 63;
    int wid = threadIdx.x >> 6;
    if (gwave >= BB * SS) return;
    int b = gwave / SS;
    const float* xb = xyz + (long)b * 3 * NN;
    float nx = new_xyz[(long)gwave * 3 + 0];
    float ny = new_xyz[(long)gwave * 3 + 1];
    float nz = new_xyz[(long)gwave * 3 + 2];
    float snew = sq3(nx, ny, nz);
    float kd[16]; int ki[16];
#pragma unroll
    for (int j = 0; j < 16; ++j) { kd[j] = 3.4e38f; ki[j] = 0x7fffffff; }
    for (int tix = 0; tix < NN / 64; ++tix) {
        int n = tix * 64 + lane;
        float qx = xb[n], qy = xb[NN + n], qz = xb[2 * NN + n];
        float sx = sq3(qx, qy, qz);
        float dot = __fadd_rn(__fadd_rn(__fmul_rn(nx, qx), __fmul_rn(ny, qy)), __fmul_rn(nz, qz));
        float d = __fsub_rn(__fadd_rn(snew, sx), __fmul_rn(2.0f, dot));
        if (d < kd[15] || (d == kd[15] && n < ki[15])) {
            kd[15] = d; ki[15] = n;
#pragma unroll
            for (int j = 15; j >= 1; --j) {
                bool sw = kd[j] < kd[j - 1] || (kd[j] == kd[j - 1] && ki[j] < ki[j - 1]);
                if (sw) {
                    float td = kd[j]; kd[j] = kd[j - 1]; kd[j - 1] = td;
                    int ti = ki[j]; ki[j] = ki[j - 1]; ki[j - 1] = ti;
                }
            }
        }
    }
    // merge 64 sorted 16-lists via LDS + 16 extraction rounds
    __shared__ float ld[4][64][17];
    __shared__ int   li[4][64][17];
#pragma unroll
    for (int j = 0; j < 16; ++j) { ld[wid][lane][j] = kd[j]; li[wid][lane][j] = ki[j]; }
    int h = 0, myres = 0;
#pragma unroll
    for (int r = 0; r < 16; ++r) {
        float cd = (h < 16) ? ld[wid][lane][h] : 3.4e38f;
        int   ci = (h < 16) ? li[wid][lane][h] : 0x7fffffff;
        float bd = cd; int bi = ci;
#pragma unroll
        for (int off = 1; off < 64; off <<= 1) {
            float od = __shfl_xor(bd, off); int oi = __shfl_xor(bi, off);
            if (od < bd || (od == bd && oi < bi)) { bd = od; bi = oi; }
        }
        if (bd == cd && bi == ci) h++;
        if (lane == r) myres = bi;
    }
    if (lane < 16) knn_idx[(long)gwave * 16 + lane] = myres;
}

// ---------------- BN0/BN1 stats pass -------------------
__global__ __launch_bounds__(256)
void mlp01_stats_kernel(const float* __restrict__ points,   // [B,64,N]
                        const float* __restrict__ xyz,      // [B,3,N]
                        const float* __restrict__ new_xyz,  // [B,S,3]
                        const int* __restrict__ knn_idx,    // [B*S,16]
                        const float* __restrict__ W0, const float* __restrict__ b0,
                        const float* __restrict__ W1, const float* __restrict__ b1,
                        float* __restrict__ sums)           // [4][64]
{
    int wid = threadIdx.x >> 6, lane = threadIdx.x & 63;
    long base = (long)blockIdx.x * 64 + wid * 16;
    float a0 = 0, q0 = 0, a1 = 0, q1 = 0;
    for (int it = 0; it < 16; ++it) {
        long pos = base + it;
        int bs = (int)(pos >> 4);
        int b = bs >> 11;
        int n = knn_idx[pos];
        float gp = points[(long)b * INCH * NN + (long)lane * NN + n];
        float x0 = b0[lane];
#pragma unroll
        for (int d = 0; d < 64; ++d)
            x0 = fmaf(__shfl(gp, d), W0[d * 64 + lane], x0);
        float nx = new_xyz[(long)bs * 3], ny = new_xyz[(long)bs * 3 + 1], nz = new_xyz[(long)bs * 3 + 2];
        const float* xb = xyz + (long)b * 3 * NN;
        float qx = xb[n], qy = xb[NN + n], qz = xb[2 * NN + n];
        float c9[9] = {nx, ny, nz, qx, qy, qz, qx - nx, qy - ny, qz - nz};
        float x1 = b1[lane];
#pragma unroll
        for (int j = 0; j < 9; ++j) x1 = fmaf(c9[j], W1[j * 64 + lane], x1);
        a0 += x0; q0 += x0 * x0; a1 += x1; q1 += x1 * x1;
    }
    __shared__ float red[4][4][64];
    red[0][wid][lane] = a0; red[1][wid][lane] = q0; red[2][wid][lane] = a1; red[3][wid][lane] = q1;
    __syncthreads();
    if (threadIdx.x < 64) {
#pragma unroll
        for (int arr = 0; arr < 4; ++arr) {
            float v = red[arr][0][lane] + red[arr][1][lane] + red[arr][2][lane] + red[arr][3][lane];
            atomicAdd(&sums[arr * 64 + lane], v);
        }
    }
}

__global__ void bn01_finalize(const float* __restrict__ sums,
                              const float* __restrict__ g0, const float* __restrict__ be0,
                              const float* __restrict__ g1, const float* __restrict__ be1,
                              float* __restrict__ ss01)
{
    int c = threadIdx.x;  // 64
    float inv = 1.0f / (float)(BB * SS * KK);
    float m0 = sums[c] * inv,        v0 = sums[64 + c] * inv - m0 * m0;
    float m1 = sums[128 + c] * inv,  v1 = sums[192 + c] * inv - m1 * m1;
    float sc0 = g0[c] / sqrtf(v0 + EPSF);
    float sc1 = g1[c] / sqrtf(v1 + EPSF);
    ss01[c] = sc0;        ss01[64 + c] = be0[c] - m0 * sc0;
    ss01[128 + c] = sc1;  ss01[192 + c] = be1[c] - m1 * sc1;
}

// ---------------- per-center fused: lse1 -> scores -> softmax -> features1 ----------
__global__ __launch_bounds__(256)
void center_kernel(const float* __restrict__ points, const float* __restrict__ xyz,
                   const float* __restrict__ new_xyz, const int* __restrict__ knn_idx,
                   const float* __restrict__ W0, const float* __restrict__ b0,
                   const float* __restrict__ W1, const float* __restrict__ b1,
                   const float* __restrict__ ss01, const float* __restrict__ Ws,
                   float* __restrict__ features1)   // [B*S,128]
{
    int bs = blockIdx.x;
    int b = bs >> 11;
    int wid = threadIdx.x >> 6, lane = threadIdx.x & 63;
    __shared__ float lse[KK][OUTC];
    __shared__ float sraw[KK][OUTC];
    float sc0 = ss01[lane], sh0 = ss01[64 + lane], sc1 = ss01[128 + lane], sh1 = ss01[192 + lane];
    float nx = new_xyz[(long)bs * 3], ny = new_xyz[(long)bs * 3 + 1], nz = new_xyz[(long)bs * 3 + 2];
    const float* xb = xyz + (long)b * 3 * NN;
#pragma unroll
    for (int kk = 0; kk < 4; ++kk) {
        int k = wid * 4 + kk;
        int n = knn_idx[(long)bs * 16 + k];
        float gp = points[(long)b * INCH * NN + (long)lane * NN + n];
        float x0 = b0[lane];
#pragma unroll
        for (int d = 0; d < 64; ++d)
            x0 = fmaf(__shfl(gp, d), W0[d * 64 + lane], x0);
        float qx = xb[n], qy = xb[NN + n], qz = xb[2 * NN + n];
        float c9[9] = {nx, ny, nz, qx, qy, qz, qx - nx, qy - ny, qz - nz};
        float x1 = b1[lane];
#pragma unroll
        for (int j = 0; j < 9; ++j) x1 = fmaf(c9[j], W1[j * 64 + lane], x1);
        x0 = leaky_f(x0 * sc0 + sh0);
        x1 = leaky_f(x1 * sc1 + sh1);
        lse[k][lane] = x1;        // channels 0..63 : lse_part (W1 path)
        lse[k][64 + lane] = x0;   // channels 64..127 : new_points (W0 path)
    }
    __syncthreads();
    // scores raw: sraw[k][d] = sum_c lse[k][c]*Ws[c][d]
    int d = threadIdx.x & 127;
    int kg = threadIdx.x >> 7;   // 0..1 -> 8 k's each
    float acc[8];
#pragma unroll
    for (int i = 0; i < 8; ++i) acc[i] = 0.f;
    for (int c = 0; c < OUTC; ++c) {
        float w = Ws[c * OUTC + d];
#pragma unroll
        for (int i = 0; i < 8; ++i) acc[i] = fmaf(lse[kg * 8 + i][c], w, acc[i]);
    }
#pragma unroll
    for (int i = 0; i < 8; ++i) sraw[kg * 8 + i][d] = leaky_f(acc[i]);
    __syncthreads();
    if (threadIdx.x < OUTC) {
        int dd = threadIdx.x;
        float vals[KK];
        float mx = -3.4e38f;
#pragma unroll
        for (int k = 0; k < KK; ++k) { vals[k] = sraw[k][dd]; mx = fmaxf(mx, vals[k]); }
        float sum = 0.f;
#pragma unroll
        for (int k = 0; k < KK; ++k) { vals[k] = __expf(vals[k] - mx); sum += vals[k]; }
        float invs = 1.0f / sum;
        float feat = 0.f;
#pragma unroll
        for (int k = 0; k < KK; ++k) feat = fmaf(vals[k] * invs, lse[k][dd], feat);
        features1[(long)bs * OUTC + dd] = feat;
    }
}

// ---------------- mlp2 GEMM + stats -------------------
__global__ __launch_bounds__(256)
void mlp2_kernel(const float* __restrict__ features1,  // [B*S,128]
                 const float* __restrict__ W2, const float* __restrict__ b2,
                 float* __restrict__ x2,               // [B*S,128]
                 float* __restrict__ sums2)            // [2][128]
{
    int p0 = blockIdx.x * 16;
    __shared__ float f[16][OUTC];
    for (int i = threadIdx.x; i < 16 * OUTC; i += 256)
        f[i >> 7][i & 127] = features1[(long)p0 * OUTC + i];
    __syncthreads();
    int d = threadIdx.x & 127;
    int g = threadIdx.x >> 7;
    float acc[8];
#pragma unroll
    for (int i = 0; i < 8; ++i) acc[i] = b2[d];
    for (int c = 0; c < OUTC; ++c) {
        float w = W2[c * OUTC + d];
#pragma unroll
        for (int i = 0; i < 8; ++i) acc[i] = fmaf(f[g * 8 + i][c], w, acc[i]);
    }
    float s = 0.f, q = 0.f;
#pragma unroll
    for (int i = 0; i < 8; ++i) {
        x2[(long)(p0 + g * 8 + i) * OUTC + d] = acc[i];
        s += acc[i]; q += acc[i] * acc[i];
    }
    __shared__ float rs[2][2][OUTC];
    rs[0][g][d] = s; rs[1][g][d] = q;
    __syncthreads();
    if (threadIdx.x < OUTC) {
        atomicAdd(&sums2[d],        rs[0][0][d] + rs[0][1][d]);
        atomicAdd(&sums2[OUTC + d], rs[1][0][d] + rs[1][1][d]);
    }
}

__global__ void bn2_finalize(const float* __restrict__ sums2,
                             const float* __restrict__ g2, const float* __restrict__ be2,
                             float* __restrict__ ss2)
{
    int c = threadIdx.x;  // 128
    float inv = 1.0f / (float)(BB * SS);
    float m = sums2[c] * inv, v = sums2[OUTC + c] * inv - m * m;
    float sc = g2[c] / sqrtf(v + EPSF);
    ss2[c] = sc; ss2[OUTC + c] = be2[c] - m * sc;
}

__global__ __launch_bounds__(256)
void out1_kernel(const float* __restrict__ x2, const float* __restrict__ ss2,
                 float* __restrict__ out1)   // [B,128,S]
{
    int bc = blockIdx.x;
    int b = bc >> 7, c = bc & 127;
    float sc = ss2[c], sh = ss2[OUTC + c];
    for (int s = threadIdx.x; s < SS; s += 256) {
        float v = x2[((long)(b * SS + s)) * OUTC + c] * sc + sh;
        out1[(long)b * OUTC * SS + (long)c * SS + s] = leaky_f(v);
    }
}

extern "C" void kernel_launch(void* const* d_in, const int* in_sizes, int n_in,
                              void* d_out, int out_size, void* d_ws, size_t ws_size,
                              hipStream_t stream)
{
    const float* xyz    = (const float*)d_in[0];
    const float* points = (const float*)d_in[1];
    const float* W0  = (const float*)d_in[2];
    const float* b0  = (const float*)d_in[3];
    const float* g0  = (const float*)d_in[4];
    const float* be0 = (const float*)d_in[5];
    const float* W1  = (const float*)d_in[6];
    const float* b1  = (const float*)d_in[7];
    const float* g1  = (const float*)d_in[8];
    const float* be1 = (const float*)d_in[9];
    const float* Ws  = (const float*)d_in[10];
    const float* W2  = (const float*)d_in[11];
    const float* b2  = (const float*)d_in[12];
    const float* g2  = (const float*)d_in[13];
    const float* be2 = (const float*)d_in[14];

    char* ws = (char*)d_ws;
    int*   fps_i  = (int*)(ws + 0);              // 32768 B
    float* nxyz   = (float*)(ws + 32768);        // 98304 B
    int*   knn_i  = (int*)(ws + 131072);         // 524288 B
    float* sums01 = (float*)(ws + 655360);       // 1024 B
    float* sums2  = (float*)(ws + 656384);       // 1024 B
    float* ss01   = (float*)(ws + 657408);       // 1024 B
    float* ss2    = (float*)(ws + 658432);       // 1024 B
    float* feat1  = (float*)(ws + 659456);       // 4 MB
    float* x2     = (float*)(ws + 659456 + 4194304); // 4 MB

    float* out0 = (float*)d_out;                       // [B,3,S]
    float* out1 = out0 + (long)BB * 3 * SS;            // [B,128,S]
    float* out2 = out1 + (long)BB * OUTC * SS;         // [B,S] float idx

    hipMemsetAsync(sums01, 0, 2048, stream);  // zero sums01 + sums2 (contiguous)

    fps_kernel<<<BB, 1024, 0, stream>>>(xyz, fps_i, nxyz, out0, out2);
    knn_kernel<<<(BB * SS) / 4, 256, 0, stream>>>(xyz, nxyz, knn_i);
    mlp01_stats_kernel<<<2048, 256, 0, stream>>>(points, xyz, nxyz, knn_i, W0, b0, W1, b1, sums01);
    bn01_finalize<<<1, 64, 0, stream>>>(sums01, g0, be0, g1, be1, ss01);
    center_kernel<<<BB * SS, 256, 0, stream>>>(points, xyz, nxyz, knn_i, W0, b0, W1, b1, ss01, Ws, feat1);
    mlp2_kernel<<<(BB * SS) / 16, 256, 0, stream>>>(feat1, W2, b2, x2, sums2);
    bn2_finalize<<<1, 128, 0, stream>>>(sums2, g2, be2, ss2);
    out1_kernel<<<BB * OUTC, 256, 0, stream>>>(x2, ss2, out1);
}